// Round 1
// 126.787 us; speedup vs baseline: 1.0773x; 1.0773x over previous
//
#include <hip/hip_runtime.h>

typedef unsigned int u32;
typedef unsigned long long u64;
typedef unsigned char u8;

// Kuhn split (needed by kA cube pass)
__constant__ int c_kuhn[6][4] = {{0,1,3,7},{0,2,3,7},{0,1,5,7},{0,2,6,7},{0,4,5,7},{0,4,6,7}};

// ntri via bitmask (verified vs NUM_TRIANGLES_TABLE for all 16 codes):
// n==1 codes {1,2,4,7,8,11,13,14} -> 0x6996 ; n==2 codes {3,5,6,9,10,12} -> 0x1668
#define N1BIT(code) ((0x6996u >> (code)) & 1u)
#define N2BIT(code) ((0x1668u >> (code)) & 1u)

// ---------------- compile-time packed per-(k,code) corner table ----------------
// For each (kuhn tet k, occupancy code): up to 6 triangle-corner entries, 6 bits each at
// bit 6*(3*tri+j):  entry = lo_corner(3b) | kb(3b)
//   lo_corner: cube-corner index of the edge endpoint with the SMALLER linear offset
//              (Kuhn tets are monotone bit-chains, so that's always the first endpoint)
//   kb:        slot of the edge delta in sorted-delta order {1,R1,R1+1,R1sq,...} minus 1
// Replaces the runtime chain c_tt -> c_kuhn -> coff[] (rodata loads) with ONE u64 load.
struct TetTbl { u64 v[6][16]; };
constexpr int TT_[16][6] = {
  {-1,-1,-1,-1,-1,-1},{1,0,2,-1,-1,-1},{4,0,3,-1,-1,-1},{1,4,2,1,3,4},
  {3,1,5,-1,-1,-1},{2,3,0,2,5,3},{1,4,0,1,5,4},{4,2,5,-1,-1,-1},
  {4,5,2,-1,-1,-1},{4,1,0,4,5,1},{3,2,0,3,5,2},{1,3,5,-1,-1,-1},
  {4,1,2,4,3,1},{3,0,4,-1,-1,-1},{2,0,1,-1,-1,-1},{-1,-1,-1,-1,-1,-1}};
constexpr int KU_[6][4] = {{0,1,3,7},{0,2,3,7},{0,1,5,7},{0,2,6,7},{0,4,5,7},{0,4,6,7}};
constexpr int E0_[6] = {0,0,0,1,1,2};
constexpr int E1_[6] = {1,2,3,2,3,3};
constexpr TetTbl make_tbl() {
  TetTbl t{};
  for (int k = 0; k < 6; k++)
    for (int code = 0; code < 16; code++) {
      u64 w = 0;
      for (int s6 = 0; s6 < 6; s6++) {
        int s = TT_[code][s6];
        if (s < 0) break;
        int ci = KU_[k][E0_[s]], cj = KU_[k][E1_[s]];
        // corner bit meanings (matches coff): bit0 -> +R1sq, bit1 -> +R1, bit2 -> +1
        int d = ci ^ cj;                                   // ci's bits are a subset of cj's
        int kbp1 = ((d & 1) << 2) | (d & 2) | ((d >> 2) & 1);
        w |= (u64)((u32)ci | (u32)((kbp1 - 1) << 3)) << (6 * s6);
      }
      t.v[k][code] = w;
    }
  return t;
}
__constant__ TetTbl g_tbl = make_tbl();

// ---------------- scan helpers (wave64) ----------------
__device__ __forceinline__ u32 wave_incscan_u32(u32 v) {
  int lane = threadIdx.x & 63;
#pragma unroll
  for (int d = 1; d < 64; d <<= 1) {
    u32 n = __shfl_up(v, (unsigned)d, 64);
    if (lane >= d) v += n;
  }
  return v;
}
__device__ __forceinline__ u64 wave_incscan_u64(u64 v) {
  int lane = threadIdx.x & 63;
#pragma unroll
  for (int d = 1; d < 64; d <<= 1) {
    u32 lo = __shfl_up((u32)v, (unsigned)d, 64);
    u32 hi = __shfl_up((u32)(v >> 32), (unsigned)d, 64);
    u64 n = ((u64)hi << 32) | (u64)lo;
    if (lane >= d) v += n;
  }
  return v;
}
__device__ __forceinline__ u32 block_exscan_u32(u32 v, u32* wsums, u32* total) {
  int tid = threadIdx.x, lane = tid & 63, w = tid >> 6, nw = blockDim.x >> 6;
  u32 inc = wave_incscan_u32(v);
  if (lane == 63) wsums[w] = inc;
  __syncthreads();
  u32 woff = 0, tot = 0;
  for (int i = 0; i < nw; i++) { u32 s = wsums[i]; tot += s; if (i < w) woff += s; }
  __syncthreads();
  if (total) *total = tot;
  return woff + inc - v;
}
__device__ __forceinline__ u64 block_exscan_u64(u64 v, u64* wsums, u64* total) {
  int tid = threadIdx.x, lane = tid & 63, w = tid >> 6, nw = blockDim.x >> 6;
  u64 inc = wave_incscan_u64(v);
  if (lane == 63) wsums[w] = inc;
  __syncthreads();
  u64 woff = 0, tot = 0;
  for (int i = 0; i < nw; i++) { u64 s = wsums[i]; tot += s; if (i < w) woff += s; }
  __syncthreads();
  if (total) *total = tot;
  return woff + inc - v;
}

// ---------------- Kernel A: vertex blocks (lpack + pos4) | cube blocks (cpack + ccodes + sums) ----
// NOTE (R6 lesson): no device fences / same-address tickets — per-XCD L2s are non-coherent; a
// per-block __threadfence()+atomic ticket cost ~470 µs. Separate 2-block kC is ~4 µs.
template <int CR>
__global__ __launch_bounds__(256) void kA(const float* __restrict__ sdf, const float* __restrict__ verts,
                                          const float* __restrict__ deform, float4* __restrict__ pos4,
                                          u32* __restrict__ lpack, u32* __restrict__ cpack,
                                          u32* __restrict__ ccodes,
                                          u32* __restrict__ bsumV, u32* __restrict__ bsumT,
                                          int NV, int Tc, int nvb, int rr, float sdefs) {
  const int R = CR ? CR : rr;
  const int R1 = R + 1, R1sq = R1 * R1;
  __shared__ u32 ws[4];
  int tid = threadIdx.x, bid = blockIdx.x;
  if (bid < nvb) {
    // ---- vertex part: crossing mask + block-local edge rank + deformed position (+sdf) ----
    int v = bid * 256 + tid;
    u32 m = 0;
    float s = 0.0f;
    if (v < NV) {
      int z = v % R1, tq = v / R1, y = tq % R1, x = tq / R1;
      s = sdf[v];
      bool o = s > 0.0f;
      bool bx = x < R, by = y < R, bz = z < R;
      if (bz && (sdf[v + 1] > 0.0f) != o) m |= 1;
      if (by && (sdf[v + R1] > 0.0f) != o) m |= 2;
      if (by && bz && (sdf[v + R1 + 1] > 0.0f) != o) m |= 4;
      if (bx && (sdf[v + R1sq] > 0.0f) != o) m |= 8;
      if (bx && bz && (sdf[v + R1sq + 1] > 0.0f) != o) m |= 16;
      if (bx && by && (sdf[v + R1sq + R1] > 0.0f) != o) m |= 32;
      if (bx && by && bz && (sdf[v + R1sq + R1 + 1] > 0.0f) != o) m |= 64;
    }
    u32 tot;
    u32 ex = block_exscan_u32(__popc(m), ws, &tot);
    if (v < NV) {
      lpack[v] = (ex << 7) | m;
      float4 p;
      p.x = verts[3 * v + 0] + sdefs * tanhf(deform[3 * v + 0]);
      p.y = verts[3 * v + 1] + sdefs * tanhf(deform[3 * v + 1]);
      p.z = verts[3 * v + 2] + sdefs * tanhf(deform[3 * v + 2]);
      p.w = s;
      pos4[v] = p;
    }
    if (tid == 0) bsumV[bid] = tot;
  } else {
    // ---- cube part: 1 thread/cube; 8 z-coalesced sdf loads -> corner mask + 6 codes + ranks ----
    int bid2 = bid - nvb;
    int c = bid2 * 256 + tid;
    u32 pk = 0;
    u32 b = 0;
    u32 cc = 0;
    if (c < Tc) {
      int z = c % R, tq = c / R, y = tq % R, x = tq / R;
      int v000 = (x * R1 + y) * R1 + z;
      int coff[8] = {0, R1sq, R1, R1sq + R1, 1, R1sq + 1, R1 + 1, R1sq + R1 + 1};
#pragma unroll
      for (int j = 0; j < 8; j++) b |= (sdf[v000 + coff[j]] > 0.0f ? 1u : 0u) << j;
#pragma unroll
      for (int k = 0; k < 6; k++) {
        int code = ((b >> c_kuhn[k][0]) & 1) | (((b >> c_kuhn[k][1]) & 1) << 1) |
                   (((b >> c_kuhn[k][2]) & 1) << 2) | (((b >> c_kuhn[k][3]) & 1) << 3);
        cc |= (u32)code << (4 * k);
        pk += N1BIT(code) + (N2BIT(code) << 16);
      }
    }
    u32 tot;
    u32 ex = block_exscan_u32(pk, ws, &tot);
    if (c < Tc) {
      u32 r1 = ex & 0xffffu, r2 = ex >> 16;        // block-local ranks, < 1536 (11 bits)
      cpack[c] = b | (r1 << 8) | (r2 << 19);       // 8 + 11 + 11 bits
      ccodes[c] = cc;                              // 6 x 4-bit tet codes
    }
    if (tid == 0) bsumT[bid2] = tot;               // m1 | m2<<16 per cube-block
  }
}

// ---------------- Kernel C: two independent aux scans ----------------
__global__ __launch_bounds__(1024) void kC(const u32* __restrict__ bsumV, u32* __restrict__ boffV,
                                           int nvb, const u32* __restrict__ bsumT,
                                           u64* __restrict__ boffT, int ncb, u32* __restrict__ hdr) {
  if (blockIdx.x == 0) {
    __shared__ u32 ws32[16];
    u32 carry = 0;
    for (int base = 0; base < nvb; base += 1024) {
      int i = base + threadIdx.x;
      u32 v = (i < nvb) ? bsumV[i] : 0;
      u32 tot;
      u32 ex = block_exscan_u32(v, ws32, &tot);
      if (i < nvb) boffV[i] = carry + ex;
      carry += tot;
    }
    if (threadIdx.x == 0) hdr[0] = carry;               // E
  } else {
    __shared__ u64 ws64[16];
    u64 carry = 0;
    for (int base = 0; base < ncb; base += 1024) {
      int i = base + threadIdx.x;
      u32 p = (i < ncb) ? bsumT[i] : 0;
      u64 v = (u64)(p & 0xffffu) | ((u64)(p >> 16) << 32);
      u64 tot;
      u64 ex = block_exscan_u64(v, ws64, &tot);
      if (i < ncb) boffT[i] = carry + ex;
      carry += tot;
    }
    if (threadIdx.x == 0) { hdr[1] = (u32)carry; hdr[2] = (u32)(carry >> 32); } // F1, F2
  }
}

// ---------------- Kernel D: uv | verts | faces — scan-free, barrier-free, one concurrent grid ------
template <int CR, int CNU>
__global__ __launch_bounds__(256) void kD(const float4* __restrict__ pos4, const u32* __restrict__ lpack,
                                          const u32* __restrict__ boffV, const u32* __restrict__ cpack,
                                          const u32* __restrict__ ccodes,
                                          const u64* __restrict__ boffT, const u32* __restrict__ hdr,
                                          float* __restrict__ out, int NV, int T, int nvb, int nuvb,
                                          int rr, int nuu, double inv) {
  const int R = CR ? CR : rr;
  const int R1 = R + 1, R1sq = R1 * R1;
  const u32 NU = CNU ? CNU : (u32)nuu;
  int tid = threadIdx.x, bid = blockIdx.x;
  u32 E = hdr[0], F1 = hdr[1], F2 = hdr[2];
  u32 F = F1 + 2u * F2;
  size_t fb = (size_t)3 * E;                     // faces section start (float index)
  size_t A = fb + (size_t)3 * F;                 // uvs section start
  size_t ub = A + (size_t)8 * NU * NU;           // uv_idx section start
  if (bid < nuvb) {
    // ---- uv writer: 8 floats/thread, ONE div, wave-uniform phase switch, two float4 stores ----
    u32 chunk = (u32)bid * 256 + tid;
    u32 sh = (u32)(A & 3);
    int totalf = (int)(8u * NU * NU);            // < 2^31
    int e0 = (int)(8u * chunk) - (int)sh;
    if (e0 >= totalf) return;
    float padf = (float)(0.9 * inv);
    // cell1 = chunk; cell0 = chunk-1 (only used when sh>0)
    u32 row1 = chunk / NU, col1 = chunk - row1 * NU;
    u32 col0 = (col1 == 0) ? (NU - 1) : (col1 - 1);
    u32 row0 = (col1 == 0) ? (row1 - 1) : row1;
    float x1 = (float)((double)col1 * inv), y1 = (float)((double)row1 * inv);
    float xp1 = x1 + padf, yp1 = y1 + padf;
    float x0 = (float)((double)col0 * inv), y0 = (float)((double)row0 * inv);
    float yp0 = y0 + padf;
    // per-cell comp order: {x, y, xp, y, xp, yp, x, yp}
    float vals[8];
    switch (sh) {
      case 0: vals[0]=x1; vals[1]=y1; vals[2]=xp1; vals[3]=y1; vals[4]=xp1; vals[5]=yp1; vals[6]=x1; vals[7]=yp1; break;
      case 1: vals[0]=yp0; vals[1]=x1; vals[2]=y1; vals[3]=xp1; vals[4]=y1; vals[5]=xp1; vals[6]=yp1; vals[7]=x1; break;
      case 2: vals[0]=x0; vals[1]=yp0; vals[2]=x1; vals[3]=y1; vals[4]=xp1; vals[5]=y1; vals[6]=xp1; vals[7]=yp1; break;
      default: vals[0]=yp0; vals[1]=x0; vals[2]=yp0; vals[3]=x1; vals[4]=y1; vals[5]=xp1; vals[6]=y1; vals[7]=xp1; break;
    }
    size_t basef = (A - sh) + 8 * (size_t)chunk;
    if (e0 >= 0 && e0 + 7 < totalf) {
      *(float4*)(out + basef)     = make_float4(vals[0], vals[1], vals[2], vals[3]);
      *(float4*)(out + basef + 4) = make_float4(vals[4], vals[5], vals[6], vals[7]);
    } else {
#pragma unroll
      for (int j = 0; j < 8; j++) {
        int e = e0 + j;
        if (e >= 0 && e < totalf) out[basef + j] = vals[j];
      }
    }
  } else if (bid < nuvb + nvb) {
    // ---- vertex writer: 1 vertex/thread; pos4 carries deformed xyz + sdf ----
    int vb = bid - nuvb;
    int v = vb * 256 + tid;
    if (v >= NV) return;
    u32 pv = lpack[v];
    u32 m = pv & 0x7fu;
    if (!m) return;
    u32 r = boffV[vb] + (pv >> 7);
    int deltas[7] = {1, R1, R1 + 1, R1sq, R1sq + 1, R1sq + R1, R1sq + R1 + 1};
    float4 a4 = pos4[v];
#pragma unroll
    for (int k = 0; k < 7; k++) {
      if ((m >> k) & 1) {
        float4 b4 = pos4[v + deltas[k]];
        float den = a4.w - b4.w;        // opposite signs -> no cancellation
        float w0 = -b4.w / den, w1 = a4.w / den;
        out[3 * r + 0] = a4.x * w0 + b4.x * w1;
        out[3 * r + 1] = a4.y * w0 + b4.y * w1;
        out[3 * r + 2] = a4.z * w0 + b4.z * w1;
        r++;
      }
    }
  } else {
    // ---- face + uv_idx writer: 1 tet/thread; codes precomputed in kA, corner decode via g_tbl ----
    int tb = bid - nuvb - nvb;
    int t = tb * 256 + tid;
    if (t >= T) return;
    int c = t / 6, k = t - 6 * c;
    u32 cp = cpack[c];                             // 6 consecutive threads share one word
    u32 b = cp & 0xffu;
    if (b == 0u || b == 0xffu) return;             // whole cube uniform -> all 6 tets empty
    u32 cc = ccodes[c];                            // 6 x 4-bit tet codes (broadcast load)
    int code = (int)((cc >> (4 * k)) & 15u);
    u32 n1 = N1BIT(code), n2 = N2BIT(code);
    int n = (int)(n1 + 2u * n2);
    if (n == 0) return;
    // intra-cube prefix ranks from code masks (pure ALU, no table walk)
    u32 m1m = 0, m2m = 0;
#pragma unroll
    for (int j = 0; j < 6; j++) {
      u32 cj = (cc >> (4 * j)) & 15u;
      m1m |= ((0x6996u >> cj) & 1u) << j;
      m2m |= ((0x1668u >> cj) & 1u) << j;
    }
    u32 pre = (1u << k) - 1u;
    u32 a1 = __popc(m1m & pre), a2 = __popc(m2m & pre);
    u64 bo = boffT[c >> 8];                        // cube-block id
    u32 s1 = (u32)bo + ((cp >> 8) & 0x7ffu) + a1;
    u32 s2 = (u32)(bo >> 32) + (cp >> 19) + a2;
    int z = c % R, tq = c / R, y = tq % R, x = tq / R;
    int v000 = (x * R1 + y) * R1 + z;
    u64 w6 = g_tbl.v[k][code];                     // ONE 8B lookup replaces c_tt/c_kuhn/coff chain
    int g4 = 4 * t;
    for (int tri = 0; tri < n; tri++) {
      u32 row = (n == 1) ? s1 : (F1 + 2u * s2 + (u32)tri);
#pragma unroll
      for (int j = 0; j < 3; j++) {
        u32 e = (u32)(w6 >> (6 * (3 * tri + j))) & 63u;
        u32 lo = e & 7u, kb = e >> 3;              // lo corner (3b) + crossing-slot (3b)
        int va = v000 + (int)(lo & 1u) * R1sq + (int)((lo >> 1) & 1u) * R1 + (int)(lo >> 2);
        u32 pv = lpack[va];
        u32 fidx = boffV[va >> 8] + (pv >> 7) + __popc(pv & 0x7fu & ((1u << kb) - 1u));
        out[fb + 3 * row + j] = (float)fidx;
      }
      out[ub + 3 * row + 0] = (float)g4;
      out[ub + 3 * row + 1] = (float)(g4 + tri + 1);
      out[ub + 3 * row + 2] = (float)(g4 + tri + 2);
    }
  }
}

extern "C" void kernel_launch(void* const* d_in, const int* in_sizes, int n_in,
                              void* d_out, int out_size, void* d_ws, size_t ws_size,
                              hipStream_t stream) {
  const float* verts = (const float*)d_in[0];
  const float* sdf = (const float*)d_in[1];
  const float* deform = (const float*)d_in[2];
  int NV = in_sizes[0] / 3;
  int T = in_sizes[3] / 4;
  int R = 1;
  while ((long long)(R + 1) * (R + 1) * (R + 1) < (long long)NV) R++;
  int NU = 1;
  while ((long long)NU * NU < (long long)T) NU++;   // N = ceil(sqrt((2T+1)//2)) = ceil(sqrt(T))
  int Tc = T / 6;                                   // cubes
  int nvb = (NV + 255) / 256;                       // vertex blocks
  int ncb = (Tc + 255) / 256;                       // cube blocks (kA) / scan entries
  int ntb = (T + 255) / 256;                        // tet (face) blocks in kD
  long long nchunks = (long long)NU * NU + 1;       // 8-float chunks incl. alignment slop
  int nuvb = (int)((nchunks + 255) / 256);          // uv blocks

  // workspace carve (16B-aligned first); ~8 MB total
  char* w = (char*)d_ws;
  float4* pos4 = (float4*)w; w += (size_t)nvb * 256 * 16;
  u64* boffT = (u64*)w; w += (size_t)ncb * 8;
  u32* cpack = (u32*)w; w += (size_t)Tc * 4;
  u32* bsumV = (u32*)w; w += (size_t)nvb * 4;
  u32* boffV = (u32*)w; w += (size_t)nvb * 4;
  u32* bsumT = (u32*)w; w += (size_t)ncb * 4;
  u32* lpack = (u32*)w; w += (size_t)nvb * 256 * 4;
  u32* hdr = (u32*)w;   w += 64;
  u32* ccodes = (u32*)w; w += (size_t)Tc * 4;

  float sdefs = 2.0f / (float)(R * 2);  // 1/64 exact
  double inv = 1.0 / (double)NU;
  float* outf = (float*)d_out;

  if (R == 64 && NU == 1255) {
    kA<64><<<dim3(nvb + ncb), dim3(256), 0, stream>>>(sdf, verts, deform, pos4, lpack, cpack,
                                                      ccodes, bsumV, bsumT, NV, Tc, nvb, R, sdefs);
    kC<<<dim3(2), dim3(1024), 0, stream>>>(bsumV, boffV, nvb, bsumT, boffT, ncb, hdr);
    kD<64, 1255><<<dim3(nuvb + nvb + ntb), dim3(256), 0, stream>>>(
        pos4, lpack, boffV, cpack, ccodes, boffT, hdr, outf, NV, T, nvb, nuvb, R, NU, inv);
  } else {
    kA<0><<<dim3(nvb + ncb), dim3(256), 0, stream>>>(sdf, verts, deform, pos4, lpack, cpack,
                                                     ccodes, bsumV, bsumT, NV, Tc, nvb, R, sdefs);
    kC<<<dim3(2), dim3(1024), 0, stream>>>(bsumV, boffV, nvb, bsumT, boffT, ncb, hdr);
    kD<0, 0><<<dim3(nuvb + nvb + ntb), dim3(256), 0, stream>>>(
        pos4, lpack, boffV, cpack, ccodes, boffT, hdr, outf, NV, T, nvb, nuvb, R, NU, inv);
  }
}